// Round 8
// baseline (227.379 us; speedup 1.0000x reference)
//
#include <hip/hip_runtime.h>

#define B_ 8
#define L_ 2048
#define E_ 256
#define H_ 4
#define D_ 64

typedef __bf16 bf16;
typedef __bf16 bf16x8 __attribute__((ext_vector_type(8)));
typedef __bf16 bf16x4 __attribute__((ext_vector_type(4)));
typedef float  f32x4  __attribute__((ext_vector_type(4)));
typedef float  f32x16 __attribute__((ext_vector_type(16)));

// Ŝ = (q·k)/8 * log2(e); softmax entirely in exp2 domain.
#define QSCALE 0.1803368801111244f

__device__ __forceinline__ float fexp2(float x) { return __builtin_amdgcn_exp2f(x); }
__device__ __forceinline__ float flog2(float x) { return __builtin_amdgcn_logf(x); }

// Barrier that drains LDS ops but NOT global loads (vmcnt stays in flight).
// Safe when all cross-wave communication is through LDS.
__device__ __forceinline__ void barrier_lds() {
    asm volatile("s_waitcnt lgkmcnt(0)" ::: "memory");
    __builtin_amdgcn_s_barrier();
}

// ---------------------------------------------------------------------------
// Kernel 0: convert x to bf16 [B,L,E]
// ---------------------------------------------------------------------------
__global__ void convert_x(const float* __restrict__ x, bf16* __restrict__ xb) {
    size_t i = ((size_t)blockIdx.x * 256 + threadIdx.x) * 4;
    f32x4 v = *(const f32x4*)&x[i];
    bf16x4 o;
#pragma unroll
    for (int j = 0; j < 4; j++) o[j] = (bf16)v[j];
    *(bf16x4*)&xb[i] = o;
}

// ---------------------------------------------------------------------------
// Kernel 1: repack weights to bf16.
// Wcat[768][256]: rows 0..511 = in_proj_w rows (q,k); rows 512..767 = W_gnn^T
// ---------------------------------------------------------------------------
__global__ void prep_weights(const float* __restrict__ in_proj_w,
                             const float* __restrict__ W_gnn,
                             bf16* __restrict__ Wcat) {
    int r = blockIdx.x;
    int e = threadIdx.x;
    float v = (r < 512) ? in_proj_w[r * E_ + e] : W_gnn[e * E_ + (r - 512)];
    Wcat[r * E_ + e] = (bf16)v;
}

// ---------------------------------------------------------------------------
// Kernel 2: projections. C[M=16384, N=768] = x @ Wcat^T (bf16 MFMA, fp32 acc)
//   by==0 -> Qs[B,L,E]  (bias + QSCALE folded; col n = h*64+d)
//   by==1 -> Ks[B,L,E]  (bias folded)
//   by==2 -> XWT[B,E,L] = (x @ W_gnn + B_gnn)^T per batch, bf16
// launch_bounds (256,4): no LDS, latency-bound on Wcat reads -> 4 waves/EU
// doubles latency hiding; acc 64 VGPR + staging ~100 < 128 cap, no spill.
// ---------------------------------------------------------------------------
__global__ __launch_bounds__(256, 4) void proj_kernel(
    const bf16* __restrict__ xb, const bf16* __restrict__ Wcat,
    const float* __restrict__ in_proj_b, const float* __restrict__ B_gnn,
    bf16* __restrict__ Qs, bf16* __restrict__ Ks, bf16* __restrict__ XWT) {
    int tid  = threadIdx.x;
    int lane = tid & 63, wave = tid >> 6;
    int l16  = lane & 15, quad = lane >> 4;
    int m0 = blockIdx.x * 64 + wave * 16;
    int by = blockIdx.y;
    int n0 = by * 256;

    f32x4 acc[16];
#pragma unroll
    for (int i = 0; i < 16; i++) acc[i] = (f32x4){0.f, 0.f, 0.f, 0.f};

    const bf16* xrow = xb + (size_t)(m0 + l16) * E_;
    for (int ks = 0; ks < 8; ks++) {
        int koff = ks * 32 + quad * 8;
        bf16x8 af = *(const bf16x8*)&xrow[koff];
#pragma unroll
        for (int nt = 0; nt < 16; nt++) {
            bf16x8 bfv = *(const bf16x8*)&Wcat[(size_t)(n0 + nt * 16 + l16) * E_ + koff];
            acc[nt] = __builtin_amdgcn_mfma_f32_16x16x32_bf16(af, bfv, acc[nt], 0, 0, 0);
        }
    }

#pragma unroll
    for (int nt = 0; nt < 16; nt++) {
        int n = n0 + nt * 16 + l16;
        if (by == 0) {
            float bias = in_proj_b[n];
#pragma unroll
            for (int r = 0; r < 4; r++) {
                int m = m0 + quad * 4 + r;
                Qs[(size_t)m * E_ + n] = (bf16)((acc[nt][r] + bias) * QSCALE);
            }
        } else if (by == 1) {
            float bias = in_proj_b[n];
            int col = n - 256;
#pragma unroll
            for (int r = 0; r < 4; r++) {
                int m = m0 + quad * 4 + r;
                Ks[(size_t)m * E_ + col] = (bf16)(acc[nt][r] + bias);
            }
        } else {
            int nc = n - 512;
            float bias = B_gnn[nc];
            int m = m0 + quad * 4;
            int b = m >> 11, l = m & 2047;
            bf16x4 pk;
#pragma unroll
            for (int r = 0; r < 4; r++) pk[r] = (bf16)(acc[nt][r] + bias);
            *(bf16x4*)&XWT[((size_t)b * E_ + nc) * L_ + l] = pk;
        }
    }
}

// ---------------------------------------------------------------------------
// Kernel 3: softmax stats (round-7 version, kept: ~11 us win).
// Double-buffered ldsK[2][64x72], reg-prefetch, ONE lgkm-only barrier/iter.
// ---------------------------------------------------------------------------
__global__ __launch_bounds__(256, 4) void stats_kernel(
    const bf16* __restrict__ Qs, const bf16* __restrict__ Ks,
    float* __restrict__ o) {
    __shared__ bf16 ldsK[2][64 * 72];
    int tid  = threadIdx.x;
    int lane = tid & 63, wave = tid >> 6;
    int r32  = lane & 31, half = lane >> 5;
    int qt = blockIdx.x, h = blockIdx.y, b = blockIdx.z;
    int q0 = qt * 128 + wave * 32;

    bf16x8 qa[4];
    const bf16* qrow = Qs + ((size_t)b * L_ + q0 + r32) * E_ + h * D_;
#pragma unroll
    for (int c = 0; c < 4; c++) qa[c] = *(const bf16x8*)&qrow[c * 16 + half * 8];

    float lsum[16];
#pragma unroll
    for (int i = 0; i < 16; i++) lsum[i] = 0.f;

    const bf16* Kb = Ks + (size_t)b * L_ * E_ + h * D_;

    // prologue: stage tile 0 into buf 0
#pragma unroll
    for (int it = 0; it < 2; it++) {
        int idx = it * 256 + tid;
        int key = idx >> 3, dc = (idx & 7) * 8;
        *(bf16x8*)&ldsK[0][key * 72 + dc] =
            *(const bf16x8*)&Kb[(size_t)key * E_ + dc];
    }
    __syncthreads();

    int cur = 0;
    for (int kt = 0; kt < 32; kt++) {
        // issue next tile's loads (in flight across the compute phase)
        bf16x8 pk0, pk1;
        if (kt < 31) {
            int idx0 = tid, idx1 = 256 + tid;
            pk0 = *(const bf16x8*)&Kb[(size_t)((kt + 1) * 64 + (idx0 >> 3)) * E_ + (idx0 & 7) * 8];
            pk1 = *(const bf16x8*)&Kb[(size_t)((kt + 1) * 64 + (idx1 >> 3)) * E_ + (idx1 & 7) * 8];
        }
        // compute from buf[cur]
#pragma unroll
        for (int nt = 0; nt < 2; nt++) {
            f32x16 S = {};
#pragma unroll
            for (int c = 0; c < 4; c++) {
                bf16x8 kb = *(const bf16x8*)&ldsK[cur][(nt * 32 + r32) * 72 + c * 16 + half * 8];
                S = __builtin_amdgcn_mfma_f32_32x32x16_bf16(qa[c], kb, S, 0, 0, 0);
            }
#pragma unroll
            for (int i = 0; i < 16; i++) lsum[i] += fexp2(S[i]);
        }
        // write prefetch to the other buffer (readers are on buf[cur])
        if (kt < 31) {
            int idx0 = tid, idx1 = 256 + tid;
            *(bf16x8*)&ldsK[cur ^ 1][(idx0 >> 3) * 72 + (idx0 & 7) * 8] = pk0;
            *(bf16x8*)&ldsK[cur ^ 1][(idx1 >> 3) * 72 + (idx1 & 7) * 8] = pk1;
        }
        barrier_lds();   // all reads of cur + writes of cur^1 drained
        cur ^= 1;
    }
#pragma unroll
    for (int i = 0; i < 16; i++) {
        float v = lsum[i];
        v += __shfl_xor(v, 1); v += __shfl_xor(v, 2); v += __shfl_xor(v, 4);
        v += __shfl_xor(v, 8); v += __shfl_xor(v, 16);
        lsum[i] = v;
    }
    if (r32 == 0) {
        float* op = o + ((size_t)(b * H_ + h)) * L_ + q0;
#pragma unroll
        for (int i = 0; i < 16; i++) {
            int row = (i & 3) + 8 * (i >> 2) + 4 * half;
            op[row] = -(2.0f + flog2(lsum[i]));
        }
    }
}

// ---------------------------------------------------------------------------
// Kernel 4: pass 2 (round-6 proven version, 65.6 us measured: T14 prefetch,
// 3 lgkm-only barriers/iter; BOTH prefetch LDS-writes after barrier A so the
// vmcnt wait lands after QK+PV have covered the load latency).
// Per iter:
//   issue tile kt+1 global loads -> regs (in flight across both barriers)
//   QK (ldsK) -> P -> ldsP ; barrier_lds (C)
//   PV (ldsXW + ldsP)       ; barrier_lds (A)
//   write prefetch regs -> ldsK/ldsXW (vmcnt wait here, ~full iter after
//   issue)                  ; barrier_lds (B)
// ---------------------------------------------------------------------------
__global__ __launch_bounds__(256, 2) void pass2_kernel(
    const bf16* __restrict__ Qs, const bf16* __restrict__ Ks,
    const bf16* __restrict__ XWT, const float* __restrict__ o,
    float* __restrict__ Opart) {
    __shared__ alignas(16) unsigned char smem[79872];
    bf16* ldsK  = (bf16*)smem;             // [64 keys][264 = 256 E + 8 pad]
    bf16* ldsXW = (bf16*)(smem + 33792);   // [256 n][72 = 64 k + 8 pad]
    bf16* ldsP  = (bf16*)(smem + 70656);   // [64 q][72 = 64 k + 8 pad]

    int tid  = threadIdx.x;
    int lane = tid & 63, wave = tid >> 6;
    int l32  = lane & 31, half = lane >> 5;
    int qh = wave & 1, kh = wave >> 1;   // QK role: q-half, k-half
    int nh = kh;                          // PV role: n-half (128 cols)

    int flat = blockIdx.x;
    int b   = flat & 7;
    int qt  = (flat >> 3) & 31;
    int ksp = flat >> 8;

    int qw = qt * 64 + qh * 32 + l32;    // this lane's q row in QK phase

    // Q B-frags for all 4 heads (B-layout: n=lane&31=q, k=(lane>>5)*8+j)
    bf16x8 qf[4][4];
    const bf16* qrow = Qs + ((size_t)b * L_ + qw) * E_;
#pragma unroll
    for (int h = 0; h < H_; h++)
#pragma unroll
        for (int c = 0; c < 4; c++)
            qf[h][c] = *(const bf16x8*)&qrow[h * 64 + c * 16 + half * 8];

    float oh[4];
#pragma unroll
    for (int h = 0; h < H_; h++)
        oh[h] = o[((size_t)(b * H_ + h)) * L_ + qw];

    f32x16 zero = {};
    f32x16 acc[4];
#pragma unroll
    for (int i = 0; i < 4; i++) acc[i] = zero;

    const bf16* Kb = Ks + (size_t)b * L_ * E_;
    const bf16* Xb = XWT + (size_t)b * E_ * L_;

    // prologue: stage tile 0 directly to LDS
    {
        int k0 = ksp * 1024;
#pragma unroll
        for (int it = 0; it < 8; it++) {
            int idx = it * 256 + tid;
            int key = idx >> 5, col = (idx & 31) * 8;
            *(bf16x8*)&ldsK[key * 264 + col] =
                *(const bf16x8*)&Kb[(size_t)(k0 + key) * E_ + col];
        }
#pragma unroll
        for (int it = 0; it < 8; it++) {
            int idx = it * 256 + tid;
            int n = idx >> 3, kc = (idx & 7) * 8;
            *(bf16x8*)&ldsXW[n * 72 + kc] =
                *(const bf16x8*)&Xb[(size_t)n * L_ + k0 + kc];
        }
    }
    __syncthreads();

    for (int kt = 0; kt < 16; kt++) {
        // issue next tile's loads into registers (no wait; stays in flight
        // across the lgkm-only barriers below)
        bf16x8 pkf[8], pxf[8];
        if (kt < 15) {
            int k1 = ksp * 1024 + (kt + 1) * 64;
#pragma unroll
            for (int it = 0; it < 8; it++) {
                int idx = it * 256 + tid;
                int key = idx >> 5, col = (idx & 31) * 8;
                pkf[it] = *(const bf16x8*)&Kb[(size_t)(k1 + key) * E_ + col];
            }
#pragma unroll
            for (int it = 0; it < 8; it++) {
                int idx = it * 256 + tid;
                int n = idx >> 3, kc = (idx & 7) * 8;
                pxf[it] = *(const bf16x8*)&Xb[(size_t)n * L_ + k1 + kc];
            }
        }

        // QK: S^T quadrant (32 keys x 32 q) per head; P = sum_h exp2(S^T+o_h)
        f32x16 P = zero;
#pragma unroll
        for (int h = 0; h < H_; h++) {
            f32x16 s = zero;
#pragma unroll
            for (int c = 0; c < 4; c++) {
                bf16x8 ka = *(const bf16x8*)&ldsK[(kh * 32 + l32) * 264 + h * 64 + c * 16 + half * 8];
                s = __builtin_amdgcn_mfma_f32_32x32x16_bf16(ka, qf[h][c], s, 0, 0, 0);
            }
#pragma unroll
            for (int r = 0; r < 16; r++) P[r] += fexp2(s[r] + oh[h]);
        }

        // write P quadrant at TRUE key indices: regs 4g..4g+3 -> keys 8g+4*half+0..3
#pragma unroll
        for (int g = 0; g < 4; g++) {
            bf16x4 pk;
#pragma unroll
            for (int j = 0; j < 4; j++) pk[j] = (bf16)P[4 * g + j];
            *(bf16x4*)&ldsP[(qh * 32 + l32) * 72 + kh * 32 + g * 8 + half * 4] = pk;
        }
        barrier_lds();   // C: P published; QK reads of ldsK drained

        // PV: O[32q x 128n] += P[32q x 64k] @ XW[64k x 128n], n-half = nh
#pragma unroll
        for (int kc = 0; kc < 4; kc++) {
            bf16x8 pa = *(const bf16x8*)&ldsP[(qh * 32 + l32) * 72 + kc * 16 + half * 8];
#pragma unroll
            for (int nt = 0; nt < 4; nt++) {
                bf16x8 xw = *(const bf16x8*)&ldsXW[(nh * 128 + nt * 32 + l32) * 72 + kc * 16 + half * 8];
                acc[nt] = __builtin_amdgcn_mfma_f32_32x32x16_bf16(pa, xw, acc[nt], 0, 0, 0);
            }
        }
        barrier_lds();   // A: PV reads drained; ldsK/ldsXW free for rewrite

        if (kt < 15) {
            // write prefetched tile to LDS (compiler inserts the vmcnt wait
            // for the register dependency here -- the only vmcnt wait)
#pragma unroll
            for (int it = 0; it < 8; it++) {
                int idx = it * 256 + tid;
                int key = idx >> 5, col = (idx & 31) * 8;
                *(bf16x8*)&ldsK[key * 264 + col] = pkf[it];
            }
#pragma unroll
            for (int it = 0; it < 8; it++) {
                int idx = it * 256 + tid;
                int n = idx >> 3, kc = (idx & 7) * 8;
                *(bf16x8*)&ldsXW[n * 72 + kc] = pxf[it];
            }
            barrier_lds();   // B: next tile published
        }
    }

    // direct quadrant store (each wave owns disjoint 32q x 128n)
    float* Ob = Opart + ((size_t)ksp * B_ + b) * (size_t)L_ * E_
              + (size_t)(qt * 64 + qh * 32) * E_ + nh * 128;
#pragma unroll
    for (int nt = 0; nt < 4; nt++)
#pragma unroll
        for (int r = 0; r < 16; r++) {
            int row = (r & 3) + 8 * (r >> 2) + 4 * half;
            Ob[(size_t)row * E_ + nt * 32 + l32] = acc[nt][r];
        }
}

// ---------------------------------------------------------------------------
// Kernel 5: sum the 2 k-half partials -> fp32 out[B,L,E]
// ---------------------------------------------------------------------------
__global__ void reduce_kernel(const float* __restrict__ Op, float* __restrict__ out) {
    size_t i = ((size_t)blockIdx.x * 256 + threadIdx.x) * 4;
    const size_t BLE = (size_t)B_ * L_ * E_;
    f32x4 a = *(const f32x4*)&Op[i];
    f32x4 c = *(const f32x4*)&Op[BLE + i];
#pragma unroll
    for (int j = 0; j < 4; j++) a[j] += c[j];
    *(f32x4*)&out[i] = a;
}

// ---------------------------------------------------------------------------
extern "C" void kernel_launch(void* const* d_in, const int* in_sizes, int n_in,
                              void* d_out, int out_size, void* d_ws, size_t ws_size,
                              hipStream_t stream) {
    const float* x   = (const float*)d_in[0];
    const float* ipw = (const float*)d_in[1];
    const float* ipb = (const float*)d_in[2];
    const float* wg  = (const float*)d_in[3];
    const float* bg  = (const float*)d_in[4];

    char* ws = (char*)d_ws;
    bf16*  Qs    = (bf16*)(ws);
    bf16*  Ks    = (bf16*)(ws + 8388608);
    bf16*  XWT   = (bf16*)(ws + 16777216);
    float* o     = (float*)(ws + 25165824);
    float* Opart = (float*)(ws + 25427968);
    bf16*  xb    = (bf16*)(ws + 25427968);
    bf16*  Wcat  = (bf16*)(ws + 33816576);

    convert_x<<<4096, 256, 0, stream>>>(x, xb);
    prep_weights<<<768, 256, 0, stream>>>(ipw, wg, Wcat);
    proj_kernel<<<dim3(256, 3), 256, 0, stream>>>(xb, Wcat, ipb, bg, Qs, Ks, XWT);
    stats_kernel<<<dim3(16, 4, 8), 256, 0, stream>>>(Qs, Ks, o);
    pass2_kernel<<<512, 256, 0, stream>>>(Qs, Ks, XWT, o, Opart);
    reduce_kernel<<<4096, 256, 0, stream>>>(Opart, (float*)d_out);
}

// Round 9
// 217.810 us; speedup vs baseline: 1.0439x; 1.0439x over previous
//
#include <hip/hip_runtime.h>

#define B_ 8
#define L_ 2048
#define E_ 256
#define H_ 4
#define D_ 64

typedef __bf16 bf16;
typedef __bf16 bf16x8 __attribute__((ext_vector_type(8)));
typedef __bf16 bf16x4 __attribute__((ext_vector_type(4)));
typedef float  f32x4  __attribute__((ext_vector_type(4)));
typedef float  f32x16 __attribute__((ext_vector_type(16)));

// Ŝ = (q·k)/8 * log2(e); softmax entirely in exp2 domain.
#define QSCALE 0.1803368801111244f

__device__ __forceinline__ float fexp2(float x) { return __builtin_amdgcn_exp2f(x); }
__device__ __forceinline__ float flog2(float x) { return __builtin_amdgcn_logf(x); }

// Barrier that drains LDS ops but NOT global loads (vmcnt stays in flight).
// Safe when all cross-wave communication is through LDS.
__device__ __forceinline__ void barrier_lds() {
    asm volatile("s_waitcnt lgkmcnt(0)" ::: "memory");
    __builtin_amdgcn_s_barrier();
}

// ---------------------------------------------------------------------------
// Kernel 0 (fused): blocks 0..4095 convert x -> bf16 xb [B,L,E];
// blocks 4096..4863 repack weights -> Wcat[768][256]
// (rows 0..511 = in_proj_w q,k rows; rows 512..767 = W_gnn^T).
// Independent work, block-disjoint -> saves one graph launch.
// ---------------------------------------------------------------------------
__global__ void prep_kernel(const float* __restrict__ x,
                            const float* __restrict__ in_proj_w,
                            const float* __restrict__ W_gnn,
                            bf16* __restrict__ xb, bf16* __restrict__ Wcat) {
    int bid = blockIdx.x;
    if (bid < 4096) {
        size_t i = ((size_t)bid * 256 + threadIdx.x) * 4;
        f32x4 v = *(const f32x4*)&x[i];
        bf16x4 o;
#pragma unroll
        for (int j = 0; j < 4; j++) o[j] = (bf16)v[j];
        *(bf16x4*)&xb[i] = o;
    } else {
        int r = bid - 4096;
        int e = threadIdx.x;
        float v = (r < 512) ? in_proj_w[r * E_ + e] : W_gnn[e * E_ + (r - 512)];
        Wcat[r * E_ + e] = (bf16)v;
    }
}

// ---------------------------------------------------------------------------
// Kernel 2: projections. C[M=16384, N=768] = x @ Wcat^T (bf16 MFMA, fp32 acc)
//   by==0 -> Qs[B,L,E]  (bias + QSCALE folded; col n = h*64+d)
//   by==1 -> Ks[B,L,E]  (bias folded)
//   by==2 -> XWT[B,E,L] = (x @ W_gnn + B_gnn)^T per batch, bf16
// launch_bounds (256,2): r8 measured (256,4) costs ~10 us — the 128-VGPR cap
// constrains B-frag staging depth in the 16-deep inner loop. Keep 2.
// ---------------------------------------------------------------------------
__global__ __launch_bounds__(256, 2) void proj_kernel(
    const bf16* __restrict__ xb, const bf16* __restrict__ Wcat,
    const float* __restrict__ in_proj_b, const float* __restrict__ B_gnn,
    bf16* __restrict__ Qs, bf16* __restrict__ Ks, bf16* __restrict__ XWT) {
    int tid  = threadIdx.x;
    int lane = tid & 63, wave = tid >> 6;
    int l16  = lane & 15, quad = lane >> 4;
    int m0 = blockIdx.x * 64 + wave * 16;
    int by = blockIdx.y;
    int n0 = by * 256;

    f32x4 acc[16];
#pragma unroll
    for (int i = 0; i < 16; i++) acc[i] = (f32x4){0.f, 0.f, 0.f, 0.f};

    const bf16* xrow = xb + (size_t)(m0 + l16) * E_;
    for (int ks = 0; ks < 8; ks++) {
        int koff = ks * 32 + quad * 8;
        bf16x8 af = *(const bf16x8*)&xrow[koff];
#pragma unroll
        for (int nt = 0; nt < 16; nt++) {
            bf16x8 bfv = *(const bf16x8*)&Wcat[(size_t)(n0 + nt * 16 + l16) * E_ + koff];
            acc[nt] = __builtin_amdgcn_mfma_f32_16x16x32_bf16(af, bfv, acc[nt], 0, 0, 0);
        }
    }

#pragma unroll
    for (int nt = 0; nt < 16; nt++) {
        int n = n0 + nt * 16 + l16;
        if (by == 0) {
            float bias = in_proj_b[n];
#pragma unroll
            for (int r = 0; r < 4; r++) {
                int m = m0 + quad * 4 + r;
                Qs[(size_t)m * E_ + n] = (bf16)((acc[nt][r] + bias) * QSCALE);
            }
        } else if (by == 1) {
            float bias = in_proj_b[n];
            int col = n - 256;
#pragma unroll
            for (int r = 0; r < 4; r++) {
                int m = m0 + quad * 4 + r;
                Ks[(size_t)m * E_ + col] = (bf16)(acc[nt][r] + bias);
            }
        } else {
            int nc = n - 512;
            float bias = B_gnn[nc];
            int m = m0 + quad * 4;
            int b = m >> 11, l = m & 2047;
            bf16x4 pk;
#pragma unroll
            for (int r = 0; r < 4; r++) pk[r] = (bf16)(acc[nt][r] + bias);
            *(bf16x4*)&XWT[((size_t)b * E_ + nc) * L_ + l] = pk;
        }
    }
}

// ---------------------------------------------------------------------------
// Kernel 3: softmax stats (r7 version, kept: ~11 us win).
// Double-buffered ldsK[2][64x72], reg-prefetch, ONE lgkm-only barrier/iter.
// ---------------------------------------------------------------------------
__global__ __launch_bounds__(256, 4) void stats_kernel(
    const bf16* __restrict__ Qs, const bf16* __restrict__ Ks,
    float* __restrict__ o) {
    __shared__ bf16 ldsK[2][64 * 72];
    int tid  = threadIdx.x;
    int lane = tid & 63, wave = tid >> 6;
    int r32  = lane & 31, half = lane >> 5;
    int qt = blockIdx.x, h = blockIdx.y, b = blockIdx.z;
    int q0 = qt * 128 + wave * 32;

    bf16x8 qa[4];
    const bf16* qrow = Qs + ((size_t)b * L_ + q0 + r32) * E_ + h * D_;
#pragma unroll
    for (int c = 0; c < 4; c++) qa[c] = *(const bf16x8*)&qrow[c * 16 + half * 8];

    float lsum[16];
#pragma unroll
    for (int i = 0; i < 16; i++) lsum[i] = 0.f;

    const bf16* Kb = Ks + (size_t)b * L_ * E_ + h * D_;

    // prologue: stage tile 0 into buf 0
#pragma unroll
    for (int it = 0; it < 2; it++) {
        int idx = it * 256 + tid;
        int key = idx >> 3, dc = (idx & 7) * 8;
        *(bf16x8*)&ldsK[0][key * 72 + dc] =
            *(const bf16x8*)&Kb[(size_t)key * E_ + dc];
    }
    __syncthreads();

    int cur = 0;
    for (int kt = 0; kt < 32; kt++) {
        // issue next tile's loads (in flight across the compute phase)
        bf16x8 pk0, pk1;
        if (kt < 31) {
            int idx0 = tid, idx1 = 256 + tid;
            pk0 = *(const bf16x8*)&Kb[(size_t)((kt + 1) * 64 + (idx0 >> 3)) * E_ + (idx0 & 7) * 8];
            pk1 = *(const bf16x8*)&Kb[(size_t)((kt + 1) * 64 + (idx1 >> 3)) * E_ + (idx1 & 7) * 8];
        }
        // compute from buf[cur]
#pragma unroll
        for (int nt = 0; nt < 2; nt++) {
            f32x16 S = {};
#pragma unroll
            for (int c = 0; c < 4; c++) {
                bf16x8 kb = *(const bf16x8*)&ldsK[cur][(nt * 32 + r32) * 72 + c * 16 + half * 8];
                S = __builtin_amdgcn_mfma_f32_32x32x16_bf16(qa[c], kb, S, 0, 0, 0);
            }
#pragma unroll
            for (int i = 0; i < 16; i++) lsum[i] += fexp2(S[i]);
        }
        // write prefetch to the other buffer (readers are on buf[cur])
        if (kt < 31) {
            int idx0 = tid, idx1 = 256 + tid;
            *(bf16x8*)&ldsK[cur ^ 1][(idx0 >> 3) * 72 + (idx0 & 7) * 8] = pk0;
            *(bf16x8*)&ldsK[cur ^ 1][(idx1 >> 3) * 72 + (idx1 & 7) * 8] = pk1;
        }
        barrier_lds();   // all reads of cur + writes of cur^1 drained
        cur ^= 1;
    }
#pragma unroll
    for (int i = 0; i < 16; i++) {
        float v = lsum[i];
        v += __shfl_xor(v, 1); v += __shfl_xor(v, 2); v += __shfl_xor(v, 4);
        v += __shfl_xor(v, 8); v += __shfl_xor(v, 16);
        lsum[i] = v;
    }
    if (r32 == 0) {
        float* op = o + ((size_t)(b * H_ + h)) * L_ + q0;
#pragma unroll
        for (int i = 0; i < 16; i++) {
            int row = (i & 3) + 8 * (i >> 2) + 4 * half;
            op[row] = -(2.0f + flog2(lsum[i]));
        }
    }
}

// ---------------------------------------------------------------------------
// Kernel 4: pass 2 (round-6 proven version, ~66 us: T14 prefetch, 3
// lgkm-only barriers/iter; BOTH prefetch LDS-writes after barrier A so the
// vmcnt wait lands after QK+PV have covered the load latency).
// ---------------------------------------------------------------------------
__global__ __launch_bounds__(256, 2) void pass2_kernel(
    const bf16* __restrict__ Qs, const bf16* __restrict__ Ks,
    const bf16* __restrict__ XWT, const float* __restrict__ o,
    float* __restrict__ Opart) {
    __shared__ alignas(16) unsigned char smem[79872];
    bf16* ldsK  = (bf16*)smem;             // [64 keys][264 = 256 E + 8 pad]
    bf16* ldsXW = (bf16*)(smem + 33792);   // [256 n][72 = 64 k + 8 pad]
    bf16* ldsP  = (bf16*)(smem + 70656);   // [64 q][72 = 64 k + 8 pad]

    int tid  = threadIdx.x;
    int lane = tid & 63, wave = tid >> 6;
    int l32  = lane & 31, half = lane >> 5;
    int qh = wave & 1, kh = wave >> 1;   // QK role: q-half, k-half
    int nh = kh;                          // PV role: n-half (128 cols)

    int flat = blockIdx.x;
    int b   = flat & 7;
    int qt  = (flat >> 3) & 31;
    int ksp = flat >> 8;

    int qw = qt * 64 + qh * 32 + l32;    // this lane's q row in QK phase

    // Q B-frags for all 4 heads (B-layout: n=lane&31=q, k=(lane>>5)*8+j)
    bf16x8 qf[4][4];
    const bf16* qrow = Qs + ((size_t)b * L_ + qw) * E_;
#pragma unroll
    for (int h = 0; h < H_; h++)
#pragma unroll
        for (int c = 0; c < 4; c++)
            qf[h][c] = *(const bf16x8*)&qrow[h * 64 + c * 16 + half * 8];

    float oh[4];
#pragma unroll
    for (int h = 0; h < H_; h++)
        oh[h] = o[((size_t)(b * H_ + h)) * L_ + qw];

    f32x16 zero = {};
    f32x16 acc[4];
#pragma unroll
    for (int i = 0; i < 4; i++) acc[i] = zero;

    const bf16* Kb = Ks + (size_t)b * L_ * E_;
    const bf16* Xb = XWT + (size_t)b * E_ * L_;

    // prologue: stage tile 0 directly to LDS
    {
        int k0 = ksp * 1024;
#pragma unroll
        for (int it = 0; it < 8; it++) {
            int idx = it * 256 + tid;
            int key = idx >> 5, col = (idx & 31) * 8;
            *(bf16x8*)&ldsK[key * 264 + col] =
                *(const bf16x8*)&Kb[(size_t)(k0 + key) * E_ + col];
        }
#pragma unroll
        for (int it = 0; it < 8; it++) {
            int idx = it * 256 + tid;
            int n = idx >> 3, kc = (idx & 7) * 8;
            *(bf16x8*)&ldsXW[n * 72 + kc] =
                *(const bf16x8*)&Xb[(size_t)n * L_ + k0 + kc];
        }
    }
    __syncthreads();

    for (int kt = 0; kt < 16; kt++) {
        // issue next tile's loads into registers (no wait; stays in flight
        // across the lgkm-only barriers below)
        bf16x8 pkf[8], pxf[8];
        if (kt < 15) {
            int k1 = ksp * 1024 + (kt + 1) * 64;
#pragma unroll
            for (int it = 0; it < 8; it++) {
                int idx = it * 256 + tid;
                int key = idx >> 5, col = (idx & 31) * 8;
                pkf[it] = *(const bf16x8*)&Kb[(size_t)(k1 + key) * E_ + col];
            }
#pragma unroll
            for (int it = 0; it < 8; it++) {
                int idx = it * 256 + tid;
                int n = idx >> 3, kc = (idx & 7) * 8;
                pxf[it] = *(const bf16x8*)&Xb[(size_t)n * L_ + k1 + kc];
            }
        }

        // QK: S^T quadrant (32 keys x 32 q) per head; P = sum_h exp2(S^T+o_h)
        f32x16 P = zero;
#pragma unroll
        for (int h = 0; h < H_; h++) {
            f32x16 s = zero;
#pragma unroll
            for (int c = 0; c < 4; c++) {
                bf16x8 ka = *(const bf16x8*)&ldsK[(kh * 32 + l32) * 264 + h * 64 + c * 16 + half * 8];
                s = __builtin_amdgcn_mfma_f32_32x32x16_bf16(ka, qf[h][c], s, 0, 0, 0);
            }
#pragma unroll
            for (int r = 0; r < 16; r++) P[r] += fexp2(s[r] + oh[h]);
        }

        // write P quadrant at TRUE key indices: regs 4g..4g+3 -> keys 8g+4*half+0..3
#pragma unroll
        for (int g = 0; g < 4; g++) {
            bf16x4 pk;
#pragma unroll
            for (int j = 0; j < 4; j++) pk[j] = (bf16)P[4 * g + j];
            *(bf16x4*)&ldsP[(qh * 32 + l32) * 72 + kh * 32 + g * 8 + half * 4] = pk;
        }
        barrier_lds();   // C: P published; QK reads of ldsK drained

        // PV: O[32q x 128n] += P[32q x 64k] @ XW[64k x 128n], n-half = nh
#pragma unroll
        for (int kc = 0; kc < 4; kc++) {
            bf16x8 pa = *(const bf16x8*)&ldsP[(qh * 32 + l32) * 72 + kc * 16 + half * 8];
#pragma unroll
            for (int nt = 0; nt < 4; nt++) {
                bf16x8 xw = *(const bf16x8*)&ldsXW[(nh * 128 + nt * 32 + l32) * 72 + kc * 16 + half * 8];
                acc[nt] = __builtin_amdgcn_mfma_f32_32x32x16_bf16(pa, xw, acc[nt], 0, 0, 0);
            }
        }
        barrier_lds();   // A: PV reads drained; ldsK/ldsXW free for rewrite

        if (kt < 15) {
            // write prefetched tile to LDS (compiler inserts the vmcnt wait
            // for the register dependency here -- the only vmcnt wait)
#pragma unroll
            for (int it = 0; it < 8; it++) {
                int idx = it * 256 + tid;
                int key = idx >> 5, col = (idx & 31) * 8;
                *(bf16x8*)&ldsK[key * 264 + col] = pkf[it];
            }
#pragma unroll
            for (int it = 0; it < 8; it++) {
                int idx = it * 256 + tid;
                int n = idx >> 3, kc = (idx & 7) * 8;
                *(bf16x8*)&ldsXW[n * 72 + kc] = pxf[it];
            }
            barrier_lds();   // B: next tile published
        }
    }

    // direct quadrant store (each wave owns disjoint 32q x 128n)
    float* Ob = Opart + ((size_t)ksp * B_ + b) * (size_t)L_ * E_
              + (size_t)(qt * 64 + qh * 32) * E_ + nh * 128;
#pragma unroll
    for (int nt = 0; nt < 4; nt++)
#pragma unroll
        for (int r = 0; r < 16; r++) {
            int row = (r & 3) + 8 * (r >> 2) + 4 * half;
            Ob[(size_t)row * E_ + nt * 32 + l32] = acc[nt][r];
        }
}

// ---------------------------------------------------------------------------
// Kernel 5: sum the 2 k-half partials -> fp32 out[B,L,E]
// ---------------------------------------------------------------------------
__global__ void reduce_kernel(const float* __restrict__ Op, float* __restrict__ out) {
    size_t i = ((size_t)blockIdx.x * 256 + threadIdx.x) * 4;
    const size_t BLE = (size_t)B_ * L_ * E_;
    f32x4 a = *(const f32x4*)&Op[i];
    f32x4 c = *(const f32x4*)&Op[BLE + i];
#pragma unroll
    for (int j = 0; j < 4; j++) a[j] += c[j];
    *(f32x4*)&out[i] = a;
}

// ---------------------------------------------------------------------------
extern "C" void kernel_launch(void* const* d_in, const int* in_sizes, int n_in,
                              void* d_out, int out_size, void* d_ws, size_t ws_size,
                              hipStream_t stream) {
    const float* x   = (const float*)d_in[0];
    const float* ipw = (const float*)d_in[1];
    const float* ipb = (const float*)d_in[2];
    const float* wg  = (const float*)d_in[3];
    const float* bg  = (const float*)d_in[4];

    char* ws = (char*)d_ws;
    bf16*  Qs    = (bf16*)(ws);
    bf16*  Ks    = (bf16*)(ws + 8388608);
    bf16*  XWT   = (bf16*)(ws + 16777216);
    float* o     = (float*)(ws + 25165824);
    float* Opart = (float*)(ws + 25427968);
    bf16*  xb    = (bf16*)(ws + 25427968);
    bf16*  Wcat  = (bf16*)(ws + 33816576);

    prep_kernel<<<4864, 256, 0, stream>>>(x, ipw, wg, xb, Wcat);
    proj_kernel<<<dim3(256, 3), 256, 0, stream>>>(xb, Wcat, ipb, bg, Qs, Ks, XWT);
    stats_kernel<<<dim3(16, 4, 8), 256, 0, stream>>>(Qs, Ks, o);
    pass2_kernel<<<512, 256, 0, stream>>>(Qs, Ks, XWT, o, Opart);
    reduce_kernel<<<4096, 256, 0, stream>>>(Opart, (float*)d_out);
}